// Round 11
// baseline (262.249 us; speedup 1.0000x reference)
//
#include <hip/hip_runtime.h>
#include <hip/hip_bf16.h>
#include <stdint.h>

#define N_NODES 20000
#define N_EDGES 640000
#define DIM     512
#define M_PAD   20096   // 157 * 128
#define NTYPE   100
#define KEXT    256     // 128 histogram + 128 one-hot
#define CSTRIDE 96      // fixed CSR row stride (mult of 32); Poisson(32) max-deg ~58
#define CURS    16      // cursor padding: one 64 B line per node (atomic de-contention)

using bf16 = __hip_bfloat16;
typedef __attribute__((ext_vector_type(4))) float floatx4;
typedef __attribute__((ext_vector_type(2))) float floatx2;
typedef __attribute__((ext_vector_type(8))) short short8;

// async global->LDS, 16B per lane. LDS dest is wave-uniform base + lane*16.
__device__ __forceinline__ void async16(const void* g, void* l) {
    __builtin_amdgcn_global_load_lds(
        (const __attribute__((address_space(1))) void*)g,
        (__attribute__((address_space(3))) void*)l, 16, 0, 0);
}

__device__ __forceinline__ uint8_t f32_to_fp8(float v) {
    unsigned p = (unsigned)__builtin_amdgcn_cvt_pk_fp8_f32(v, v, 0, false);
    return (uint8_t)(p & 0xffu);
}

// ---------------- fused setup ----------------
// blocks [0,512): transpose Ws1/Wn1 fp32[k][n] -> Wt[n][k] bf16   (bf16: fp8 weights failed R8)
// blocks [512,1024): project emb through Ws0/Wn0 -> Pb [512][KEXT] bf16
// blocks [1024,1337): zero cursor (80000 uint4)
__global__ __launch_bounds__(256)
void setup_kernel(const float* __restrict__ Ws0, const float* __restrict__ Wn0,
                  const float* __restrict__ Ws1, const float* __restrict__ Wn1,
                  const float* __restrict__ emb, bf16* __restrict__ Wt,
                  bf16* __restrict__ Pb, int* __restrict__ cursor) {
    __shared__ float tile[32][33];
    const int b = blockIdx.x;
    const int tid = threadIdx.x;
    if (b < 512) {
        const int w = b >> 8;
        const int rem = b & 255;
        const int k0 = (rem & 15) * 32;
        const int n0 = (rem >> 4) * 32;
        const float* W = (w == 0) ? Ws1 : Wn1;
        const int tx = tid & 31, ty = tid >> 5;
#pragma unroll
        for (int i = 0; i < 4; ++i)
            tile[ty + i * 8][tx] = W[(size_t)(k0 + ty + i * 8) * DIM + n0 + tx];
        __syncthreads();
        bf16* O = Wt + (size_t)w * DIM * DIM;
#pragma unroll
        for (int i = 0; i < 4; ++i)
            O[(size_t)(n0 + ty + i * 8) * DIM + k0 + tx] = __float2bfloat16(tile[tx][ty + i * 8]);
    } else if (b < 1024) {
        const int pb = b - 512;
        const int w = pb >> 8;                         // 0: Ws0 (one-hot half), 1: Wn0
        const int idx = (pb & 255) * 256 + tid;        // [0, 65536)
        const int t = idx >> 9;                        // [0,128)
        const int n = idx & 511;
        bf16* dstp = Pb + (size_t)n * KEXT + ((w == 0) ? (128 + t) : t);
        if (t >= NTYPE) { *dstp = __float2bfloat16(0.0f); return; }
        const float* W = (w == 0) ? Ws0 : Wn0;
        const float* erow = emb + (size_t)t * DIM;
        float s = 0.0f;
#pragma unroll 8
        for (int k = 0; k < DIM; ++k) s += erow[k] * W[(size_t)k * DIM + n];
        *dstp = __float2bfloat16(s);
    } else {
        const int idx = (b - 1024) * 256 + tid;
        if (idx < (N_NODES * CURS) / 4) {
            uint4 z; z.x = 0; z.y = 0; z.z = 0; z.w = 0;
            ((uint4*)cursor)[idx] = z;
        }
    }
}

// ---------------- CSR fill: 1 de-contended atomic/edge, feat packed into entry ----------------
__global__ void graph_kernel(const int* __restrict__ src, const int* __restrict__ dst,
                             const int* __restrict__ feat, int* __restrict__ cursor,
                             int* __restrict__ csr) {
    const int e = blockIdx.x * 256 + threadIdx.x;
    if (e < N_EDGES) {
        const int d = dst[e];
        const int s = src[e];
        const int t = feat[s];
        const int p = atomicAdd(&cursor[d * CURS], 1);   // private line per node
        if (p < CSTRIDE) csr[d * CSTRIDE + p] = s | (t << 16);
    }
}

// ---------------- A0 [M_PAD][KEXT] from CSR via LDS hist; pads csr rows to mult-of-32 ----------------
// Pad entries point at row N_NODES (zeroed in h8 by gemm0) so aggregate needs no predication.
__global__ void normalize_kernel(const int* __restrict__ csr, const int* __restrict__ cursor,
                                 const int* __restrict__ feat, bf16* __restrict__ A0,
                                 int* __restrict__ csr_w) {
    __shared__ int hist[4 * 128];
    const int tid = threadIdx.x;
    hist[tid] = 0;
    hist[tid + 256] = 0;
    __syncthreads();
    const int wave = tid >> 6, lane = tid & 63;
    const int node = blockIdx.x * 4 + wave;            // grid.x = 5024 exactly
    int dg = 0;
    if (node < N_NODES) {
        dg = cursor[node * CURS];
        if (dg > CSTRIDE) dg = CSTRIDE;
        for (int l = lane; l < dg; l += 64) {
            const int v = csr[node * CSTRIDE + l];
            atomicAdd(&hist[wave * 128 + (v >> 16)], 1);
        }
        // pad csr row to multiple of 32 with the zero-row index (4-deep ILP in aggregate)
        const int dgp = (dg + 31) & ~31;               // <= 96 = CSTRIDE
        for (int l = dg + lane; l < dgp; l += 64)
            csr_w[node * CSTRIDE + l] = N_NODES;
    }
    __syncthreads();
    const int c = lane * 4;                            // cols c..c+3 of KEXT
    union { uint2 u; bf16 b[4]; } o;
    if (node < N_NODES) {
        if (c < 128) {
            const float inv = 1.0f / (float)(dg > 0 ? dg : 1);
#pragma unroll
            for (int q = 0; q < 4; ++q)
                o.b[q] = __float2bfloat16((float)hist[wave * 128 + c + q] * inv);
        } else {
            const int f = feat[node];
#pragma unroll
            for (int q = 0; q < 4; ++q)
                o.b[q] = __float2bfloat16((c - 128 + q == f) ? 1.0f : 0.0f);
        }
    } else {
#pragma unroll
        for (int q = 0; q < 4; ++q) o.b[q] = __float2bfloat16(0.0f);
    }
    *(uint2*)(A0 + (size_t)node * KEXT + c) = o.u;
}

// ---------------- mean aggregation: plane-split, 32 edges/iter (4-deep ILP), 32-bit addr ----------------
// grid (5000, 4): y = plane (128 B slice; 2.5 MB L2-resident working set, x-major dispatch).
// Wave = (node, plane). eg = lane>>3 (edge slot), sc = lane&7 (16 B sub-chunk).
// Four independent edge loads in flight per lane; row offset (s<<9)+colb fits 32 bits (<2^24).
__global__ void aggregate_kernel(const uint8_t* __restrict__ h8, const int* __restrict__ cursor,
                                 const int* __restrict__ csr, bf16* __restrict__ hn) {
    const int tid = threadIdx.x;
    const int nb = blockIdx.x;                         // node group, grid.x = 5000
    const int p = blockIdx.y;
    const int wave = tid >> 6, lane = tid & 63;
    const int node = nb * 4 + wave;
    int dg = cursor[node * CURS];
    if (dg > CSTRIDE) dg = CSTRIDE;
    const int dgp = (dg + 31) & ~31;                   // csr padded by normalize
    const int eg = lane >> 3, sc = lane & 7;
    const int base = node * CSTRIDE;
    const unsigned colb = p * 128 + sc * 16;           // byte offset in fp8 row
    floatx2 acc[8] = {};                               // acc[a] = dims (2a, 2a+1) of lane's 16

    for (int i = 0; i < dgp; i += 32) {
        const unsigned s0 = (unsigned)(csr[base + i + eg]      & 0xffff);
        const unsigned s1 = (unsigned)(csr[base + i + 8 + eg]  & 0xffff);
        const unsigned s2 = (unsigned)(csr[base + i + 16 + eg] & 0xffff);
        const unsigned s3 = (unsigned)(csr[base + i + 24 + eg] & 0xffff);
        const uint4 r0 = *(const uint4*)(h8 + ((s0 << 9) + colb));
        const uint4 r1 = *(const uint4*)(h8 + ((s1 << 9) + colb));
        const uint4 r2 = *(const uint4*)(h8 + ((s2 << 9) + colb));
        const uint4 r3 = *(const uint4*)(h8 + ((s3 << 9) + colb));
        const unsigned v0[4] = {r0.x, r0.y, r0.z, r0.w};
        const unsigned v1[4] = {r1.x, r1.y, r1.z, r1.w};
        const unsigned v2[4] = {r2.x, r2.y, r2.z, r2.w};
        const unsigned v3[4] = {r3.x, r3.y, r3.z, r3.w};
#pragma unroll
        for (int q = 0; q < 4; ++q) {
            acc[2 * q]     += __builtin_amdgcn_cvt_pk_f32_fp8((int)v0[q], false);
            acc[2 * q + 1] += __builtin_amdgcn_cvt_pk_f32_fp8((int)v0[q], true);
            acc[2 * q]     += __builtin_amdgcn_cvt_pk_f32_fp8((int)v1[q], false);
            acc[2 * q + 1] += __builtin_amdgcn_cvt_pk_f32_fp8((int)v1[q], true);
            acc[2 * q]     += __builtin_amdgcn_cvt_pk_f32_fp8((int)v2[q], false);
            acc[2 * q + 1] += __builtin_amdgcn_cvt_pk_f32_fp8((int)v2[q], true);
            acc[2 * q]     += __builtin_amdgcn_cvt_pk_f32_fp8((int)v3[q], false);
            acc[2 * q + 1] += __builtin_amdgcn_cvt_pk_f32_fp8((int)v3[q], true);
        }
    }
#pragma unroll
    for (int mk = 8; mk <= 32; mk <<= 1)
#pragma unroll
        for (int q = 0; q < 8; ++q) {
            float lo = acc[q][0], hi = acc[q][1];
            acc[q][0] = lo + __shfl_xor(lo, mk, 64);
            acc[q][1] = hi + __shfl_xor(hi, mk, 64);
        }

    if (eg == 0) {
        const float scale = 1.0f / (float)(dg > 0 ? dg : 1);
        union { uint4 u; bf16 b[8]; } o0, o1;
#pragma unroll
        for (int q = 0; q < 4; ++q) {
            o0.b[2 * q]     = __float2bfloat16(acc[q][0] * scale);
            o0.b[2 * q + 1] = __float2bfloat16(acc[q][1] * scale);
            o1.b[2 * q]     = __float2bfloat16(acc[4 + q][0] * scale);
            o1.b[2 * q + 1] = __float2bfloat16(acc[4 + q][1] * scale);
        }
        bf16* outp = hn + (size_t)node * DIM + colb;
        *(uint4*)outp = o0.u;
        *(uint4*)(outp + 8) = o1.u;
    }
}

// ---------------- layer-0 GEMM: h1 = relu(A0 @ Pb^T + b0) -> bf16 h1 + fp8 h8, K=256 ----------------
__global__ __launch_bounds__(256)
void gemm0_kernel(const bf16* __restrict__ A0, const bf16* __restrict__ Pb,
                  const float* __restrict__ bias, bf16* __restrict__ h1,
                  uint8_t* __restrict__ h8) {
    const int tid  = threadIdx.x;
    const int lane = tid & 63;
    const int wave = tid >> 6;
    const int wm = wave & 1, wn = wave >> 1;
    const int gn = blockIdx.x, gm = blockIdx.y;        // gm slow: A-tile temporal locality
    const int lrow = lane & 15;
    const int kq   = lane >> 4;

    floatx4 acc[4][4] = {};
#pragma unroll
    for (int kk = 0; kk < KEXT; kk += 32) {
        short8 af[4], bfr[4];
#pragma unroll
        for (int i = 0; i < 4; ++i)
            af[i] = *(const short8*)(A0 + (size_t)(gm * 128 + wm * 64 + i * 16 + lrow) * KEXT + kk + kq * 8);
#pragma unroll
        for (int j = 0; j < 4; ++j)
            bfr[j] = *(const short8*)(Pb + (size_t)(gn * 128 + wn * 64 + j * 16 + lrow) * KEXT + kk + kq * 8);
#pragma unroll
        for (int i = 0; i < 4; ++i)
#pragma unroll
            for (int j = 0; j < 4; ++j)
                acc[i][j] = __builtin_amdgcn_mfma_f32_16x16x32_bf16(af[i], bfr[j], acc[i][j], 0, 0, 0);
    }

    // C/D layout: col=lane&15, row=(lane>>4)*4+reg  [m89/m91]
    const int colInTile = lane & 15;
    const int rquad = lane >> 4;
    float bv[4];
#pragma unroll
    for (int j = 0; j < 4; ++j) bv[j] = bias[gn * 128 + wn * 64 + j * 16 + colInTile];
#pragma unroll
    for (int i = 0; i < 4; ++i) {
#pragma unroll
        for (int r = 0; r < 4; ++r) {
            const int mrow = gm * 128 + wm * 64 + i * 16 + rquad * 4 + r;
            if (mrow >= N_NODES) {
                if (mrow < M_PAD) {
#pragma unroll
                    for (int j = 0; j < 4; ++j) {
                        const int ncol = gn * 128 + wn * 64 + j * 16 + colInTile;
                        h1[(size_t)mrow * DIM + ncol] = __float2bfloat16(0.0f);
                        h8[(size_t)mrow * DIM + ncol] = 0;   // zero rows incl. the pad target
                    }
                }
                continue;
            }
#pragma unroll
            for (int j = 0; j < 4; ++j) {
                const int ncol = gn * 128 + wn * 64 + j * 16 + colInTile;
                float v = acc[i][j][r] + bv[j];
                v = v > 0.0f ? v : 0.0f;
                h1[(size_t)mrow * DIM + ncol] = __float2bfloat16(v);
                h8[(size_t)mrow * DIM + ncol] = f32_to_fp8(v);
            }
        }
    }
}

// ---------------- layer-1 fused dual-GEMM bf16 (K=1024): XOR-swizzled single-buffer LDS ----------------
// 32 KB LDS + launch_bounds(256,4): 4 blocks/CU -> all 628 blocks co-resident (no tail).
__global__ __launch_bounds__(256, 4)
void gemm1_kernel(const bf16* __restrict__ A, const bf16* __restrict__ Nh,
                  const bf16* __restrict__ Bst, const bf16* __restrict__ Bnt,
                  const float* __restrict__ bias, float* __restrict__ out) {
    __shared__ bf16 As[128 * 64];
    __shared__ bf16 Bs[128 * 64];
    const int tid  = threadIdx.x;
    const int lane = tid & 63;
    const int wave = tid >> 6;
    const int wm = wave & 1, wn = wave >> 1;
    const int gn = blockIdx.x, gm = blockIdx.y;        // gm slow: A-tile temporal locality

    floatx4 acc[4][4] = {};
    const int lrow = lane & 15;
    const int kq   = lane >> 4;

    for (int kt = 0; kt < 16; ++kt) {
        const bf16* Ap = (kt < 8) ? A : Nh;
        const bf16* Bp = (kt < 8) ? Bst : Bnt;
        const int k0 = (kt & 7) * 64;
        __syncthreads();                               // protect LDS reuse
#pragma unroll
        for (int it = 0; it < 4; ++it) {
            const int chunk = tid + it * 256;          // LDS chunk (uniform base + lane*16)
            const int row = chunk >> 3;
            const int ch  = (chunk & 7) ^ (row & 7);   // swizzled global source
            async16(Ap + (size_t)(gm * 128 + row) * DIM + k0 + ch * 8, As + chunk * 8);
            async16(Bp + (size_t)(gn * 128 + row) * DIM + k0 + ch * 8, Bs + chunk * 8);
        }
        __syncthreads();                               // staging complete (vmcnt drained)
#pragma unroll
        for (int kk8 = 0; kk8 < 8; kk8 += 4) {
            short8 af[4], bfr[4];
#pragma unroll
            for (int i = 0; i < 4; ++i) {
                const int r = wm * 64 + i * 16 + lrow;
                af[i] = *(const short8*)(As + (r * 8 + ((kq + kk8) ^ (r & 7))) * 8);
            }
#pragma unroll
            for (int j = 0; j < 4; ++j) {
                const int r = wn * 64 + j * 16 + lrow;
                bfr[j] = *(const short8*)(Bs + (r * 8 + ((kq + kk8) ^ (r & 7))) * 8);
            }
#pragma unroll
            for (int i = 0; i < 4; ++i)
#pragma unroll
                for (int j = 0; j < 4; ++j)
                    acc[i][j] = __builtin_amdgcn_mfma_f32_16x16x32_bf16(af[i], bfr[j], acc[i][j], 0, 0, 0);
        }
    }

    const int colInTile = lane & 15;
    const int rquad = lane >> 4;
    float bv[4];
#pragma unroll
    for (int j = 0; j < 4; ++j) bv[j] = bias[gn * 128 + wn * 64 + j * 16 + colInTile];
#pragma unroll
    for (int i = 0; i < 4; ++i) {
#pragma unroll
        for (int j = 0; j < 4; ++j) {
            const int ncol = gn * 128 + wn * 64 + j * 16 + colInTile;
#pragma unroll
            for (int r = 0; r < 4; ++r) {
                const int mrow = gm * 128 + wm * 64 + i * 16 + rquad * 4 + r;
                if (mrow < N_NODES) {
                    float v = acc[i][j][r] + bv[j];
                    out[(size_t)mrow * DIM + ncol] = v > 0.0f ? v : 0.0f;
                }
            }
        }
    }
}

// ---------------- launch ----------------
extern "C" void kernel_launch(void* const* d_in, const int* in_sizes, int n_in,
                              void* d_out, int out_size, void* d_ws, size_t ws_size,
                              hipStream_t stream) {
    const int*   feat = (const int*)d_in[0];
    const int*   src  = (const int*)d_in[1];
    const int*   dst  = (const int*)d_in[2];
    const float* emb  = (const float*)d_in[3];
    const float* Ws0  = (const float*)d_in[4];
    const float* Wn0  = (const float*)d_in[5];
    const float* b0   = (const float*)d_in[6];
    const float* Ws1  = (const float*)d_in[7];
    const float* Wn1  = (const float*)d_in[8];
    const float* b1   = (const float*)d_in[9];
    float* out = (float*)d_out;

    uint8_t* w = (uint8_t*)d_ws;
    auto alloc = [&](size_t bytes) -> void* {
        void* p = (void*)w;
        w += (bytes + 255) & ~(size_t)255;
        return p;
    };
    bf16*     h1      = (bf16*)alloc((size_t)M_PAD * DIM * 2);     // bf16 h1
    uint8_t*  h8      = (uint8_t*)alloc((size_t)M_PAD * DIM);      // fp8 h1 (gather copy, pad rows zeroed)
    bf16*     hn      = (bf16*)alloc((size_t)M_PAD * DIM * 2);     // bf16 neighbor mean
    bf16*     Wt      = (bf16*)alloc((size_t)2 * DIM * DIM * 2);   // Wst1, Wnt1 bf16 [n][k]
    bf16*     Pb      = (bf16*)alloc((size_t)DIM * KEXT * 2);
    bf16*     A0      = (bf16*)alloc((size_t)M_PAD * KEXT * 2);
    int*      cursor  = (int*)alloc((size_t)N_NODES * CURS * 4);   // 1.28 MB, 1 line/node
    int*      csr     = (int*)alloc((size_t)N_NODES * CSTRIDE * 4);// 7.68 MB

    // fused setup: weight transpose + embedding projection + cursor zeroing
    setup_kernel<<<1337, 256, 0, stream>>>(Ws0, Wn0, Ws1, Wn1, emb, Wt, Pb, cursor);

    graph_kernel<<<N_EDGES / 256, 256, 0, stream>>>(src, dst, feat, cursor, csr);
    normalize_kernel<<<M_PAD / 4, 256, 0, stream>>>(csr, cursor, feat, A0, csr);

    // layer 0 (histogram + one-hot form), emits bf16 h1 and fp8 h8
    gemm0_kernel<<<dim3(4, 157), 256, 0, stream>>>(A0, Pb, b0, h1, h8);

    // layer 1
    aggregate_kernel<<<dim3(5000, 4), 256, 0, stream>>>(h8, cursor, csr, hn);
    gemm1_kernel<<<dim3(4, 157), 256, 0, stream>>>(
        h1, hn, Wt, Wt + DIM * DIM, b1, out);
}

// Round 12
// 252.914 us; speedup vs baseline: 1.0369x; 1.0369x over previous
//
#include <hip/hip_runtime.h>
#include <hip/hip_bf16.h>
#include <stdint.h>

#define N_NODES 20000
#define N_EDGES 640000
#define DIM     512
#define M_PAD   20096   // 157 * 128
#define NTYPE   100
#define KEXT    256     // 128 histogram + 128 one-hot
#define CSTRIDE 96      // fixed CSR row stride; Poisson(32) max-deg ~58 over 20K draws
#define CURS    16      // cursor padding: one 64 B line per node (atomic de-contention)

using bf16 = __hip_bfloat16;
typedef __attribute__((ext_vector_type(4))) float floatx4;
typedef __attribute__((ext_vector_type(2))) float floatx2;
typedef __attribute__((ext_vector_type(8))) short short8;

// async global->LDS, 16B per lane. LDS dest is wave-uniform base + lane*16.
__device__ __forceinline__ void async16(const void* g, void* l) {
    __builtin_amdgcn_global_load_lds(
        (const __attribute__((address_space(1))) void*)g,
        (__attribute__((address_space(3))) void*)l, 16, 0, 0);
}

__device__ __forceinline__ uint8_t f32_to_fp8(float v) {
    unsigned p = (unsigned)__builtin_amdgcn_cvt_pk_fp8_f32(v, v, 0, false);
    return (uint8_t)(p & 0xffu);
}

// ---------------- fused setup ----------------
// blocks [0,512): transpose Ws1/Wn1 fp32[k][n] -> Wt[n][k] bf16   (bf16: fp8 weights failed R8)
// blocks [512,1024): project emb through Ws0/Wn0 -> Pb [512][KEXT] bf16
// blocks [1024,1337): zero cursor (80000 uint4)
__global__ __launch_bounds__(256)
void setup_kernel(const float* __restrict__ Ws0, const float* __restrict__ Wn0,
                  const float* __restrict__ Ws1, const float* __restrict__ Wn1,
                  const float* __restrict__ emb, bf16* __restrict__ Wt,
                  bf16* __restrict__ Pb, int* __restrict__ cursor) {
    __shared__ float tile[32][33];
    const int b = blockIdx.x;
    const int tid = threadIdx.x;
    if (b < 512) {
        const int w = b >> 8;
        const int rem = b & 255;
        const int k0 = (rem & 15) * 32;
        const int n0 = (rem >> 4) * 32;
        const float* W = (w == 0) ? Ws1 : Wn1;
        const int tx = tid & 31, ty = tid >> 5;
#pragma unroll
        for (int i = 0; i < 4; ++i)
            tile[ty + i * 8][tx] = W[(size_t)(k0 + ty + i * 8) * DIM + n0 + tx];
        __syncthreads();
        bf16* O = Wt + (size_t)w * DIM * DIM;
#pragma unroll
        for (int i = 0; i < 4; ++i)
            O[(size_t)(n0 + ty + i * 8) * DIM + k0 + tx] = __float2bfloat16(tile[tx][ty + i * 8]);
    } else if (b < 1024) {
        const int pb = b - 512;
        const int w = pb >> 8;                         // 0: Ws0 (one-hot half), 1: Wn0
        const int idx = (pb & 255) * 256 + tid;        // [0, 65536)
        const int t = idx >> 9;                        // [0,128)
        const int n = idx & 511;
        bf16* dstp = Pb + (size_t)n * KEXT + ((w == 0) ? (128 + t) : t);
        if (t >= NTYPE) { *dstp = __float2bfloat16(0.0f); return; }
        const float* W = (w == 0) ? Ws0 : Wn0;
        const float* erow = emb + (size_t)t * DIM;
        float s = 0.0f;
#pragma unroll 8
        for (int k = 0; k < DIM; ++k) s += erow[k] * W[(size_t)k * DIM + n];
        *dstp = __float2bfloat16(s);
    } else {
        const int idx = (b - 1024) * 256 + tid;
        if (idx < (N_NODES * CURS) / 4) {
            uint4 z; z.x = 0; z.y = 0; z.z = 0; z.w = 0;
            ((uint4*)cursor)[idx] = z;
        }
    }
}

// ---------------- CSR fill: 4 edges/thread (independent atomic chains), feat packed ----------------
__global__ void graph_kernel(const int* __restrict__ src, const int* __restrict__ dst,
                             const int* __restrict__ feat, int* __restrict__ cursor,
                             int* __restrict__ csr) {
    const int idx = blockIdx.x * 256 + threadIdx.x;    // grid = 625 -> 160000 threads x 4 edges
    const int4 s4 = ((const int4*)src)[idx];
    const int4 d4 = ((const int4*)dst)[idx];
    const int s[4] = {s4.x, s4.y, s4.z, s4.w};
    const int d[4] = {d4.x, d4.y, d4.z, d4.w};
    int t[4], p[4];
#pragma unroll
    for (int q = 0; q < 4; ++q) t[q] = feat[s[q]];
#pragma unroll
    for (int q = 0; q < 4; ++q) p[q] = atomicAdd(&cursor[d[q] * CURS], 1);
#pragma unroll
    for (int q = 0; q < 4; ++q)
        if (p[q] < CSTRIDE) csr[d[q] * CSTRIDE + p[q]] = s[q] | (t[q] << 16);
}

// ---------------- A0 [M_PAD][KEXT] from CSR via LDS hist; pads csr rows to mult-of-16 ----------------
// Pad entries point at row N_NODES (zeroed in h8 by gemm0) so aggregate needs no predication.
__global__ void normalize_kernel(const int* __restrict__ csr, const int* __restrict__ cursor,
                                 const int* __restrict__ feat, bf16* __restrict__ A0,
                                 int* __restrict__ csr_w) {
    __shared__ int hist[4 * 128];
    const int tid = threadIdx.x;
    hist[tid] = 0;
    hist[tid + 256] = 0;
    __syncthreads();
    const int wave = tid >> 6, lane = tid & 63;
    const int node = blockIdx.x * 4 + wave;            // grid.x = 5024 exactly
    int dg = 0;
    if (node < N_NODES) {
        dg = cursor[node * CURS];
        if (dg > CSTRIDE) dg = CSTRIDE;
        for (int l = lane; l < dg; l += 64) {
            const int v = csr[node * CSTRIDE + l];
            atomicAdd(&hist[wave * 128 + (v >> 16)], 1);
        }
        // pad csr row to multiple of 16 with the zero-row index (2-deep ILP in aggregate)
        const int dgp = (dg + 15) & ~15;               // <= 96 = CSTRIDE
        for (int l = dg + lane; l < dgp; l += 64)
            csr_w[node * CSTRIDE + l] = N_NODES;
    }
    __syncthreads();
    const int c = lane * 4;                            // cols c..c+3 of KEXT
    union { uint2 u; bf16 b[4]; } o;
    if (node < N_NODES) {
        if (c < 128) {
            const float inv = 1.0f / (float)(dg > 0 ? dg : 1);
#pragma unroll
            for (int q = 0; q < 4; ++q)
                o.b[q] = __float2bfloat16((float)hist[wave * 128 + c + q] * inv);
        } else {
            const int f = feat[node];
#pragma unroll
            for (int q = 0; q < 4; ++q)
                o.b[q] = __float2bfloat16((c - 128 + q == f) ? 1.0f : 0.0f);
        }
    } else {
#pragma unroll
        for (int q = 0; q < 4; ++q) o.b[q] = __float2bfloat16(0.0f);
    }
    *(uint2*)(A0 + (size_t)node * KEXT + c) = o.u;
}

// ---------------- mean aggregation: plane-split, 16 edges/iter (R10 optimum), 32-bit addr ----------------
// grid (5000, 4): y = plane (128 B slice; 2.5 MB L2-resident working set, x-major dispatch).
// Wave = (node, plane). eg = lane>>3 (edge slot), sc = lane&7 (16 B sub-chunk).
// Two independent edge loads in flight per lane; row offset (s<<9)+colb fits 32 bits (<2^24).
__global__ void aggregate_kernel(const uint8_t* __restrict__ h8, const int* __restrict__ cursor,
                                 const int* __restrict__ csr, bf16* __restrict__ hn) {
    const int tid = threadIdx.x;
    const int nb = blockIdx.x;                         // node group, grid.x = 5000
    const int p = blockIdx.y;
    const int wave = tid >> 6, lane = tid & 63;
    const int node = nb * 4 + wave;
    int dg = cursor[node * CURS];
    if (dg > CSTRIDE) dg = CSTRIDE;
    const int dgp = (dg + 15) & ~15;                   // csr padded by normalize
    const int eg = lane >> 3, sc = lane & 7;
    const int base = node * CSTRIDE;
    const unsigned colb = p * 128 + sc * 16;           // byte offset in fp8 row
    floatx2 acc[8] = {};                               // acc[a] = dims (2a, 2a+1) of lane's 16

    for (int i = 0; i < dgp; i += 16) {
        const unsigned s0 = (unsigned)(csr[base + i + eg]     & 0xffff);
        const unsigned s1 = (unsigned)(csr[base + i + 8 + eg] & 0xffff);
        const uint4 r0 = *(const uint4*)(h8 + ((s0 << 9) + colb));
        const uint4 r1 = *(const uint4*)(h8 + ((s1 << 9) + colb));
        const unsigned v0[4] = {r0.x, r0.y, r0.z, r0.w};
        const unsigned v1[4] = {r1.x, r1.y, r1.z, r1.w};
#pragma unroll
        for (int q = 0; q < 4; ++q) {
            acc[2 * q]     += __builtin_amdgcn_cvt_pk_f32_fp8((int)v0[q], false);
            acc[2 * q + 1] += __builtin_amdgcn_cvt_pk_f32_fp8((int)v0[q], true);
        }
#pragma unroll
        for (int q = 0; q < 4; ++q) {
            acc[2 * q]     += __builtin_amdgcn_cvt_pk_f32_fp8((int)v1[q], false);
            acc[2 * q + 1] += __builtin_amdgcn_cvt_pk_f32_fp8((int)v1[q], true);
        }
    }
#pragma unroll
    for (int mk = 8; mk <= 32; mk <<= 1)
#pragma unroll
        for (int q = 0; q < 8; ++q) {
            float lo = acc[q][0], hi = acc[q][1];
            acc[q][0] = lo + __shfl_xor(lo, mk, 64);
            acc[q][1] = hi + __shfl_xor(hi, mk, 64);
        }

    if (eg == 0) {
        const float scale = 1.0f / (float)(dg > 0 ? dg : 1);
        union { uint4 u; bf16 b[8]; } o0, o1;
#pragma unroll
        for (int q = 0; q < 4; ++q) {
            o0.b[2 * q]     = __float2bfloat16(acc[q][0] * scale);
            o0.b[2 * q + 1] = __float2bfloat16(acc[q][1] * scale);
            o1.b[2 * q]     = __float2bfloat16(acc[4 + q][0] * scale);
            o1.b[2 * q + 1] = __float2bfloat16(acc[4 + q][1] * scale);
        }
        bf16* outp = hn + (size_t)node * DIM + colb;
        *(uint4*)outp = o0.u;
        *(uint4*)(outp + 8) = o1.u;
    }
}

// ---------------- layer-0 GEMM: h1 = relu(A0 @ Pb^T + b0) -> bf16 h1 + fp8 h8, K=256 ----------------
__global__ __launch_bounds__(256)
void gemm0_kernel(const bf16* __restrict__ A0, const bf16* __restrict__ Pb,
                  const float* __restrict__ bias, bf16* __restrict__ h1,
                  uint8_t* __restrict__ h8) {
    const int tid  = threadIdx.x;
    const int lane = tid & 63;
    const int wave = tid >> 6;
    const int wm = wave & 1, wn = wave >> 1;
    const int gn = blockIdx.x, gm = blockIdx.y;        // gm slow: A-tile temporal locality
    const int lrow = lane & 15;
    const int kq   = lane >> 4;

    floatx4 acc[4][4] = {};
#pragma unroll
    for (int kk = 0; kk < KEXT; kk += 32) {
        short8 af[4], bfr[4];
#pragma unroll
        for (int i = 0; i < 4; ++i)
            af[i] = *(const short8*)(A0 + (size_t)(gm * 128 + wm * 64 + i * 16 + lrow) * KEXT + kk + kq * 8);
#pragma unroll
        for (int j = 0; j < 4; ++j)
            bfr[j] = *(const short8*)(Pb + (size_t)(gn * 128 + wn * 64 + j * 16 + lrow) * KEXT + kk + kq * 8);
#pragma unroll
        for (int i = 0; i < 4; ++i)
#pragma unroll
            for (int j = 0; j < 4; ++j)
                acc[i][j] = __builtin_amdgcn_mfma_f32_16x16x32_bf16(af[i], bfr[j], acc[i][j], 0, 0, 0);
    }

    // C/D layout: col=lane&15, row=(lane>>4)*4+reg  [m89/m91]
    const int colInTile = lane & 15;
    const int rquad = lane >> 4;
    float bv[4];
#pragma unroll
    for (int j = 0; j < 4; ++j) bv[j] = bias[gn * 128 + wn * 64 + j * 16 + colInTile];
#pragma unroll
    for (int i = 0; i < 4; ++i) {
#pragma unroll
        for (int r = 0; r < 4; ++r) {
            const int mrow = gm * 128 + wm * 64 + i * 16 + rquad * 4 + r;
            if (mrow >= N_NODES) {
                if (mrow < M_PAD) {
#pragma unroll
                    for (int j = 0; j < 4; ++j) {
                        const int ncol = gn * 128 + wn * 64 + j * 16 + colInTile;
                        h1[(size_t)mrow * DIM + ncol] = __float2bfloat16(0.0f);
                        h8[(size_t)mrow * DIM + ncol] = 0;   // zero rows incl. the pad target
                    }
                }
                continue;
            }
#pragma unroll
            for (int j = 0; j < 4; ++j) {
                const int ncol = gn * 128 + wn * 64 + j * 16 + colInTile;
                float v = acc[i][j][r] + bv[j];
                v = v > 0.0f ? v : 0.0f;
                h1[(size_t)mrow * DIM + ncol] = __float2bfloat16(v);
                h8[(size_t)mrow * DIM + ncol] = f32_to_fp8(v);
            }
        }
    }
}

// ---------------- layer-1 fused dual-GEMM bf16 (K=1024): XOR-swizzled single-buffer LDS ----------------
// 32 KB LDS + launch_bounds(256,4): 4 blocks/CU -> all 628 blocks co-resident (no tail).
__global__ __launch_bounds__(256, 4)
void gemm1_kernel(const bf16* __restrict__ A, const bf16* __restrict__ Nh,
                  const bf16* __restrict__ Bst, const bf16* __restrict__ Bnt,
                  const float* __restrict__ bias, float* __restrict__ out) {
    __shared__ bf16 As[128 * 64];
    __shared__ bf16 Bs[128 * 64];
    const int tid  = threadIdx.x;
    const int lane = tid & 63;
    const int wave = tid >> 6;
    const int wm = wave & 1, wn = wave >> 1;
    const int gn = blockIdx.x, gm = blockIdx.y;        // gm slow: A-tile temporal locality

    floatx4 acc[4][4] = {};
    const int lrow = lane & 15;
    const int kq   = lane >> 4;

    for (int kt = 0; kt < 16; ++kt) {
        const bf16* Ap = (kt < 8) ? A : Nh;
        const bf16* Bp = (kt < 8) ? Bst : Bnt;
        const int k0 = (kt & 7) * 64;
        __syncthreads();                               // protect LDS reuse
#pragma unroll
        for (int it = 0; it < 4; ++it) {
            const int chunk = tid + it * 256;          // LDS chunk (uniform base + lane*16)
            const int row = chunk >> 3;
            const int ch  = (chunk & 7) ^ (row & 7);   // swizzled global source
            async16(Ap + (size_t)(gm * 128 + row) * DIM + k0 + ch * 8, As + chunk * 8);
            async16(Bp + (size_t)(gn * 128 + row) * DIM + k0 + ch * 8, Bs + chunk * 8);
        }
        __syncthreads();                               // staging complete (vmcnt drained)
#pragma unroll
        for (int kk8 = 0; kk8 < 8; kk8 += 4) {
            short8 af[4], bfr[4];
#pragma unroll
            for (int i = 0; i < 4; ++i) {
                const int r = wm * 64 + i * 16 + lrow;
                af[i] = *(const short8*)(As + (r * 8 + ((kq + kk8) ^ (r & 7))) * 8);
            }
#pragma unroll
            for (int j = 0; j < 4; ++j) {
                const int r = wn * 64 + j * 16 + lrow;
                bfr[j] = *(const short8*)(Bs + (r * 8 + ((kq + kk8) ^ (r & 7))) * 8);
            }
#pragma unroll
            for (int i = 0; i < 4; ++i)
#pragma unroll
                for (int j = 0; j < 4; ++j)
                    acc[i][j] = __builtin_amdgcn_mfma_f32_16x16x32_bf16(af[i], bfr[j], acc[i][j], 0, 0, 0);
        }
    }

    const int colInTile = lane & 15;
    const int rquad = lane >> 4;
    float bv[4];
#pragma unroll
    for (int j = 0; j < 4; ++j) bv[j] = bias[gn * 128 + wn * 64 + j * 16 + colInTile];
#pragma unroll
    for (int i = 0; i < 4; ++i) {
#pragma unroll
        for (int j = 0; j < 4; ++j) {
            const int ncol = gn * 128 + wn * 64 + j * 16 + colInTile;
#pragma unroll
            for (int r = 0; r < 4; ++r) {
                const int mrow = gm * 128 + wm * 64 + i * 16 + rquad * 4 + r;
                if (mrow < N_NODES) {
                    float v = acc[i][j][r] + bv[j];
                    out[(size_t)mrow * DIM + ncol] = v > 0.0f ? v : 0.0f;
                }
            }
        }
    }
}

// ---------------- launch ----------------
extern "C" void kernel_launch(void* const* d_in, const int* in_sizes, int n_in,
                              void* d_out, int out_size, void* d_ws, size_t ws_size,
                              hipStream_t stream) {
    const int*   feat = (const int*)d_in[0];
    const int*   src  = (const int*)d_in[1];
    const int*   dst  = (const int*)d_in[2];
    const float* emb  = (const float*)d_in[3];
    const float* Ws0  = (const float*)d_in[4];
    const float* Wn0  = (const float*)d_in[5];
    const float* b0   = (const float*)d_in[6];
    const float* Ws1  = (const float*)d_in[7];
    const float* Wn1  = (const float*)d_in[8];
    const float* b1   = (const float*)d_in[9];
    float* out = (float*)d_out;

    uint8_t* w = (uint8_t*)d_ws;
    auto alloc = [&](size_t bytes) -> void* {
        void* p = (void*)w;
        w += (bytes + 255) & ~(size_t)255;
        return p;
    };
    bf16*     h1      = (bf16*)alloc((size_t)M_PAD * DIM * 2);     // bf16 h1
    uint8_t*  h8      = (uint8_t*)alloc((size_t)M_PAD * DIM);      // fp8 h1 (gather copy, pad rows zeroed)
    bf16*     hn      = (bf16*)alloc((size_t)M_PAD * DIM * 2);     // bf16 neighbor mean
    bf16*     Wt      = (bf16*)alloc((size_t)2 * DIM * DIM * 2);   // Wst1, Wnt1 bf16 [n][k]
    bf16*     Pb      = (bf16*)alloc((size_t)DIM * KEXT * 2);
    bf16*     A0      = (bf16*)alloc((size_t)M_PAD * KEXT * 2);
    int*      cursor  = (int*)alloc((size_t)N_NODES * CURS * 4);   // 1.28 MB, 1 line/node
    int*      csr     = (int*)alloc((size_t)N_NODES * CSTRIDE * 4);// 7.68 MB

    // fused setup: weight transpose + embedding projection + cursor zeroing
    setup_kernel<<<1337, 256, 0, stream>>>(Ws0, Wn0, Ws1, Wn1, emb, Wt, Pb, cursor);

    graph_kernel<<<N_EDGES / 1024, 256, 0, stream>>>(src, dst, feat, cursor, csr);
    normalize_kernel<<<M_PAD / 4, 256, 0, stream>>>(csr, cursor, feat, A0, csr);

    // layer 0 (histogram + one-hot form), emits bf16 h1 and fp8 h8
    gemm0_kernel<<<dim3(4, 157), 256, 0, stream>>>(A0, Pb, b0, h1, h8);

    // layer 1
    aggregate_kernel<<<dim3(5000, 4), 256, 0, stream>>>(h8, cursor, csr, hn);
    gemm1_kernel<<<dim3(4, 157), 256, 0, stream>>>(
        h1, hn, Wt, Wt + DIM * DIM, b1, out);
}

// Round 13
// 240.099 us; speedup vs baseline: 1.0923x; 1.0534x over previous
//
#include <hip/hip_runtime.h>
#include <hip/hip_bf16.h>
#include <stdint.h>

#define N_NODES 20000
#define N_EDGES 640000
#define DIM     512
#define M_PAD   20096   // 157 * 128
#define NTYPE   100
#define KEXT    256     // 128 histogram + 128 one-hot
#define CSTRIDE 96      // fixed CSR row stride; Poisson(32) max-deg ~58 over 20K draws
#define CURS    16      // cursor padding: one 64 B line per node (atomic de-contention)

using bf16 = __hip_bfloat16;
typedef __attribute__((ext_vector_type(4))) float floatx4;
typedef __attribute__((ext_vector_type(2))) float floatx2;
typedef __attribute__((ext_vector_type(8))) short short8;

// async global->LDS, 16B per lane. LDS dest is wave-uniform base + lane*16.
__device__ __forceinline__ void async16(const void* g, void* l) {
    __builtin_amdgcn_global_load_lds(
        (const __attribute__((address_space(1))) void*)g,
        (__attribute__((address_space(3))) void*)l, 16, 0, 0);
}

__device__ __forceinline__ uint8_t f32_to_fp8(float v) {
    unsigned p = (unsigned)__builtin_amdgcn_cvt_pk_fp8_f32(v, v, 0, false);
    return (uint8_t)(p & 0xffu);
}

// ---------------- fused setup ----------------
// blocks [0,1024): transpose {Ws1,Wn1,Ws0,Wn0} fp32[k][n] -> Wt[w][n][k] bf16
// blocks [1024,1056): cast emb -> embB [128][512] bf16 (t>=100 zeroed)
// blocks [1056,1369): zero cursor (80000 uint4)
__global__ __launch_bounds__(256)
void setup_kernel(const float* __restrict__ Ws0, const float* __restrict__ Wn0,
                  const float* __restrict__ Ws1, const float* __restrict__ Wn1,
                  const float* __restrict__ emb, bf16* __restrict__ Wt,
                  bf16* __restrict__ embB, int* __restrict__ cursor) {
    __shared__ float tile[32][33];
    const int b = blockIdx.x;
    const int tid = threadIdx.x;
    if (b < 1024) {
        const int w = b >> 8;                          // 0:Ws1 1:Wn1 2:Ws0 3:Wn0
        const int rem = b & 255;
        const int k0 = (rem & 15) * 32;
        const int n0 = (rem >> 4) * 32;
        const float* W = (w == 0) ? Ws1 : (w == 1) ? Wn1 : (w == 2) ? Ws0 : Wn0;
        const int tx = tid & 31, ty = tid >> 5;
#pragma unroll
        for (int i = 0; i < 4; ++i)
            tile[ty + i * 8][tx] = W[(size_t)(k0 + ty + i * 8) * DIM + n0 + tx];
        __syncthreads();
        bf16* O = Wt + (size_t)w * DIM * DIM;
#pragma unroll
        for (int i = 0; i < 4; ++i)
            O[(size_t)(n0 + ty + i * 8) * DIM + k0 + tx] = __float2bfloat16(tile[tx][ty + i * 8]);
    } else if (b < 1056) {
        const int idx = (b - 1024) * 2048 + tid * 8;   // [0, 65536), 8 elems/thread
        const int t = idx >> 9;
        union { uint4 u; bf16 v[8]; } o;
        if (t < NTYPE) {
            const float* e = emb + idx;
#pragma unroll
            for (int q = 0; q < 8; ++q) o.v[q] = __float2bfloat16(e[q]);
        } else {
#pragma unroll
            for (int q = 0; q < 8; ++q) o.v[q] = __float2bfloat16(0.0f);
        }
        *(uint4*)(embB + idx) = o.u;
    } else {
        const int idx = (b - 1056) * 256 + tid;
        if (idx < (N_NODES * CURS) / 4) {
            uint4 z; z.x = 0; z.y = 0; z.z = 0; z.w = 0;
            ((uint4*)cursor)[idx] = z;
        }
    }
}

// ---------------- MFMA proj: Pb[n][t]/[n][128+t] = (embB @ {Wn0,Ws0})^T ----------------
// M=128 (t), N'=1024 (Ws0t then Wn0t, contiguous at Wt+2*DIM*DIM), K=512. grid = 8 (gn).
// Direct L2 fragment loads (operands tiny). Epilogue scatter-writes the transposed Pb layout:
// n'<512 -> Ws0 -> Pb[n'][128+t] (one-hot half); n'>=512 -> Wn0 -> Pb[n'-512][t] (hist half).
__global__ __launch_bounds__(256)
void projmm_kernel(const bf16* __restrict__ embB, const bf16* __restrict__ Wt,
                   bf16* __restrict__ Pb) {
    const int tid  = threadIdx.x;
    const int lane = tid & 63;
    const int wave = tid >> 6;
    const int wm = wave & 1, wn = wave >> 1;
    const int gn = blockIdx.x;
    const int lrow = lane & 15;
    const int kq   = lane >> 4;
    const bf16* WB = Wt + (size_t)2 * DIM * DIM;       // Ws0t then Wn0t, 1024 rows of 512

    floatx4 acc[4][4] = {};
#pragma unroll 4
    for (int kk = 0; kk < DIM; kk += 32) {
        short8 af[4], bfr[4];
#pragma unroll
        for (int i = 0; i < 4; ++i)
            af[i] = *(const short8*)(embB + (size_t)(wm * 64 + i * 16 + lrow) * DIM + kk + kq * 8);
#pragma unroll
        for (int j = 0; j < 4; ++j)
            bfr[j] = *(const short8*)(WB + (size_t)(gn * 128 + wn * 64 + j * 16 + lrow) * DIM + kk + kq * 8);
#pragma unroll
        for (int i = 0; i < 4; ++i)
#pragma unroll
            for (int j = 0; j < 4; ++j)
                acc[i][j] = __builtin_amdgcn_mfma_f32_16x16x32_bf16(af[i], bfr[j], acc[i][j], 0, 0, 0);
    }

    const int colInTile = lane & 15;
    const int rquad = lane >> 4;
#pragma unroll
    for (int i = 0; i < 4; ++i)
#pragma unroll
        for (int j = 0; j < 4; ++j) {
            const int np = gn * 128 + wn * 64 + j * 16 + colInTile;   // [0,1024)
#pragma unroll
            for (int r = 0; r < 4; ++r) {
                const int t = wm * 64 + i * 16 + rquad * 4 + r;       // [0,128)
                const int n = np & 511;
                const int pcol = (np < 512) ? (128 + t) : t;
                Pb[(size_t)n * KEXT + pcol] = __float2bfloat16(acc[i][j][r]);
            }
        }
}

// ---------------- CSR fill: 4 edges/thread (independent atomic chains), feat packed ----------------
__global__ void graph_kernel(const int* __restrict__ src, const int* __restrict__ dst,
                             const int* __restrict__ feat, int* __restrict__ cursor,
                             int* __restrict__ csr) {
    const int idx = blockIdx.x * 256 + threadIdx.x;    // grid = 625 -> 160000 threads x 4 edges
    const int4 s4 = ((const int4*)src)[idx];
    const int4 d4 = ((const int4*)dst)[idx];
    const int s[4] = {s4.x, s4.y, s4.z, s4.w};
    const int d[4] = {d4.x, d4.y, d4.z, d4.w};
    int t[4], p[4];
#pragma unroll
    for (int q = 0; q < 4; ++q) t[q] = feat[s[q]];
#pragma unroll
    for (int q = 0; q < 4; ++q) p[q] = atomicAdd(&cursor[d[q] * CURS], 1);
#pragma unroll
    for (int q = 0; q < 4; ++q)
        if (p[q] < CSTRIDE) csr[d[q] * CSTRIDE + p[q]] = s[q] | (t[q] << 16);
}

// ---------------- A0 [M_PAD][KEXT] from CSR via LDS hist; pads csr rows to mult-of-16 ----------------
// Pad entries point at row N_NODES (zeroed in h8 by gemm0) so aggregate needs no predication.
__global__ void normalize_kernel(const int* __restrict__ csr, const int* __restrict__ cursor,
                                 const int* __restrict__ feat, bf16* __restrict__ A0,
                                 int* __restrict__ csr_w) {
    __shared__ int hist[4 * 128];
    const int tid = threadIdx.x;
    hist[tid] = 0;
    hist[tid + 256] = 0;
    __syncthreads();
    const int wave = tid >> 6, lane = tid & 63;
    const int node = blockIdx.x * 4 + wave;            // grid.x = 5024 exactly
    int dg = 0;
    if (node < N_NODES) {
        dg = cursor[node * CURS];
        if (dg > CSTRIDE) dg = CSTRIDE;
        for (int l = lane; l < dg; l += 64) {
            const int v = csr[node * CSTRIDE + l];
            atomicAdd(&hist[wave * 128 + (v >> 16)], 1);
        }
        // pad csr row to multiple of 16 with the zero-row index (2-deep ILP in aggregate)
        const int dgp = (dg + 15) & ~15;               // <= 96 = CSTRIDE
        for (int l = dg + lane; l < dgp; l += 64)
            csr_w[node * CSTRIDE + l] = N_NODES;
    }
    __syncthreads();
    const int c = lane * 4;                            // cols c..c+3 of KEXT
    union { uint2 u; bf16 b[4]; } o;
    if (node < N_NODES) {
        if (c < 128) {
            const float inv = 1.0f / (float)(dg > 0 ? dg : 1);
#pragma unroll
            for (int q = 0; q < 4; ++q)
                o.b[q] = __float2bfloat16((float)hist[wave * 128 + c + q] * inv);
        } else {
            const int f = feat[node];
#pragma unroll
            for (int q = 0; q < 4; ++q)
                o.b[q] = __float2bfloat16((c - 128 + q == f) ? 1.0f : 0.0f);
        }
    } else {
#pragma unroll
        for (int q = 0; q < 4; ++q) o.b[q] = __float2bfloat16(0.0f);
    }
    *(uint2*)(A0 + (size_t)node * KEXT + c) = o.u;
}

// ---------------- mean aggregation: plane-split, 16 edges/iter (R10 optimum), 32-bit addr ----------------
// grid (5000, 4): y = plane (128 B slice; 2.5 MB L2-resident working set, x-major dispatch).
__global__ void aggregate_kernel(const uint8_t* __restrict__ h8, const int* __restrict__ cursor,
                                 const int* __restrict__ csr, bf16* __restrict__ hn) {
    const int tid = threadIdx.x;
    const int nb = blockIdx.x;                         // node group, grid.x = 5000
    const int p = blockIdx.y;
    const int wave = tid >> 6, lane = tid & 63;
    const int node = nb * 4 + wave;
    int dg = cursor[node * CURS];
    if (dg > CSTRIDE) dg = CSTRIDE;
    const int dgp = (dg + 15) & ~15;                   // csr padded by normalize
    const int eg = lane >> 3, sc = lane & 7;
    const int base = node * CSTRIDE;
    const unsigned colb = p * 128 + sc * 16;           // byte offset in fp8 row
    floatx2 acc[8] = {};                               // acc[a] = dims (2a, 2a+1) of lane's 16

    for (int i = 0; i < dgp; i += 16) {
        const unsigned s0 = (unsigned)(csr[base + i + eg]     & 0xffff);
        const unsigned s1 = (unsigned)(csr[base + i + 8 + eg] & 0xffff);
        const uint4 r0 = *(const uint4*)(h8 + ((s0 << 9) + colb));
        const uint4 r1 = *(const uint4*)(h8 + ((s1 << 9) + colb));
        const unsigned v0[4] = {r0.x, r0.y, r0.z, r0.w};
        const unsigned v1[4] = {r1.x, r1.y, r1.z, r1.w};
#pragma unroll
        for (int q = 0; q < 4; ++q) {
            acc[2 * q]     += __builtin_amdgcn_cvt_pk_f32_fp8((int)v0[q], false);
            acc[2 * q + 1] += __builtin_amdgcn_cvt_pk_f32_fp8((int)v0[q], true);
        }
#pragma unroll
        for (int q = 0; q < 4; ++q) {
            acc[2 * q]     += __builtin_amdgcn_cvt_pk_f32_fp8((int)v1[q], false);
            acc[2 * q + 1] += __builtin_amdgcn_cvt_pk_f32_fp8((int)v1[q], true);
        }
    }
#pragma unroll
    for (int mk = 8; mk <= 32; mk <<= 1)
#pragma unroll
        for (int q = 0; q < 8; ++q) {
            float lo = acc[q][0], hi = acc[q][1];
            acc[q][0] = lo + __shfl_xor(lo, mk, 64);
            acc[q][1] = hi + __shfl_xor(hi, mk, 64);
        }

    if (eg == 0) {
        const float scale = 1.0f / (float)(dg > 0 ? dg : 1);
        union { uint4 u; bf16 b[8]; } o0, o1;
#pragma unroll
        for (int q = 0; q < 4; ++q) {
            o0.b[2 * q]     = __float2bfloat16(acc[q][0] * scale);
            o0.b[2 * q + 1] = __float2bfloat16(acc[q][1] * scale);
            o1.b[2 * q]     = __float2bfloat16(acc[4 + q][0] * scale);
            o1.b[2 * q + 1] = __float2bfloat16(acc[4 + q][1] * scale);
        }
        bf16* outp = hn + (size_t)node * DIM + colb;
        *(uint4*)outp = o0.u;
        *(uint4*)(outp + 8) = o1.u;
    }
}

// ---------------- layer-0 GEMM (LDS-staged): h1 = relu(A0 @ Pb^T + b0) -> bf16 h1 + fp8 h8 ----------------
// K=256, BK=64 (4 iters), XOR-swizzled global_load_lds staging, 32 KB LDS, 4 blocks/CU.
__global__ __launch_bounds__(256, 4)
void gemm0_kernel(const bf16* __restrict__ A0, const bf16* __restrict__ Pb,
                  const float* __restrict__ bias, bf16* __restrict__ h1,
                  uint8_t* __restrict__ h8) {
    __shared__ bf16 As[128 * 64];
    __shared__ bf16 Bs[128 * 64];
    const int tid  = threadIdx.x;
    const int lane = tid & 63;
    const int wave = tid >> 6;
    const int wm = wave & 1, wn = wave >> 1;
    const int gn = blockIdx.x, gm = blockIdx.y;        // gm slow: A-tile temporal locality
    const int lrow = lane & 15;
    const int kq   = lane >> 4;

    floatx4 acc[4][4] = {};
    for (int kt = 0; kt < 4; ++kt) {
        const int k0 = kt * 64;
        __syncthreads();                               // protect LDS reuse
#pragma unroll
        for (int it = 0; it < 4; ++it) {
            const int chunk = tid + it * 256;          // LDS chunk (uniform base + lane*16)
            const int row = chunk >> 3;
            const int ch  = (chunk & 7) ^ (row & 7);   // swizzled global source
            async16(A0 + (size_t)(gm * 128 + row) * KEXT + k0 + ch * 8, As + chunk * 8);
            async16(Pb + (size_t)(gn * 128 + row) * KEXT + k0 + ch * 8, Bs + chunk * 8);
        }
        __syncthreads();                               // staging complete
#pragma unroll
        for (int kk8 = 0; kk8 < 8; kk8 += 4) {
            short8 af[4], bfr[4];
#pragma unroll
            for (int i = 0; i < 4; ++i) {
                const int r = wm * 64 + i * 16 + lrow;
                af[i] = *(const short8*)(As + (r * 8 + ((kq + kk8) ^ (r & 7))) * 8);
            }
#pragma unroll
            for (int j = 0; j < 4; ++j) {
                const int r = wn * 64 + j * 16 + lrow;
                bfr[j] = *(const short8*)(Bs + (r * 8 + ((kq + kk8) ^ (r & 7))) * 8);
            }
#pragma unroll
            for (int i = 0; i < 4; ++i)
#pragma unroll
                for (int j = 0; j < 4; ++j)
                    acc[i][j] = __builtin_amdgcn_mfma_f32_16x16x32_bf16(af[i], bfr[j], acc[i][j], 0, 0, 0);
        }
    }

    // C/D layout: col=lane&15, row=(lane>>4)*4+reg  [m89/m91]
    const int colInTile = lane & 15;
    const int rquad = lane >> 4;
    float bv[4];
#pragma unroll
    for (int j = 0; j < 4; ++j) bv[j] = bias[gn * 128 + wn * 64 + j * 16 + colInTile];
#pragma unroll
    for (int i = 0; i < 4; ++i) {
#pragma unroll
        for (int r = 0; r < 4; ++r) {
            const int mrow = gm * 128 + wm * 64 + i * 16 + rquad * 4 + r;
            if (mrow >= N_NODES) {
                if (mrow < M_PAD) {
#pragma unroll
                    for (int j = 0; j < 4; ++j) {
                        const int ncol = gn * 128 + wn * 64 + j * 16 + colInTile;
                        h1[(size_t)mrow * DIM + ncol] = __float2bfloat16(0.0f);
                        h8[(size_t)mrow * DIM + ncol] = 0;   // zero rows incl. the pad target
                    }
                }
                continue;
            }
#pragma unroll
            for (int j = 0; j < 4; ++j) {
                const int ncol = gn * 128 + wn * 64 + j * 16 + colInTile;
                float v = acc[i][j][r] + bv[j];
                v = v > 0.0f ? v : 0.0f;
                h1[(size_t)mrow * DIM + ncol] = __float2bfloat16(v);
                h8[(size_t)mrow * DIM + ncol] = f32_to_fp8(v);
            }
        }
    }
}

// ---------------- layer-1 fused dual-GEMM bf16 (K=1024): XOR-swizzled single-buffer LDS ----------------
__global__ __launch_bounds__(256, 4)
void gemm1_kernel(const bf16* __restrict__ A, const bf16* __restrict__ Nh,
                  const bf16* __restrict__ Bst, const bf16* __restrict__ Bnt,
                  const float* __restrict__ bias, float* __restrict__ out) {
    __shared__ bf16 As[128 * 64];
    __shared__ bf16 Bs[128 * 64];
    const int tid  = threadIdx.x;
    const int lane = tid & 63;
    const int wave = tid >> 6;
    const int wm = wave & 1, wn = wave >> 1;
    const int gn = blockIdx.x, gm = blockIdx.y;        // gm slow: A-tile temporal locality

    floatx4 acc[4][4] = {};
    const int lrow = lane & 15;
    const int kq   = lane >> 4;

    for (int kt = 0; kt < 16; ++kt) {
        const bf16* Ap = (kt < 8) ? A : Nh;
        const bf16* Bp = (kt < 8) ? Bst : Bnt;
        const int k0 = (kt & 7) * 64;
        __syncthreads();                               // protect LDS reuse
#pragma unroll
        for (int it = 0; it < 4; ++it) {
            const int chunk = tid + it * 256;          // LDS chunk (uniform base + lane*16)
            const int row = chunk >> 3;
            const int ch  = (chunk & 7) ^ (row & 7);   // swizzled global source
            async16(Ap + (size_t)(gm * 128 + row) * DIM + k0 + ch * 8, As + chunk * 8);
            async16(Bp + (size_t)(gn * 128 + row) * DIM + k0 + ch * 8, Bs + chunk * 8);
        }
        __syncthreads();                               // staging complete (vmcnt drained)
#pragma unroll
        for (int kk8 = 0; kk8 < 8; kk8 += 4) {
            short8 af[4], bfr[4];
#pragma unroll
            for (int i = 0; i < 4; ++i) {
                const int r = wm * 64 + i * 16 + lrow;
                af[i] = *(const short8*)(As + (r * 8 + ((kq + kk8) ^ (r & 7))) * 8);
            }
#pragma unroll
            for (int j = 0; j < 4; ++j) {
                const int r = wn * 64 + j * 16 + lrow;
                bfr[j] = *(const short8*)(Bs + (r * 8 + ((kq + kk8) ^ (r & 7))) * 8);
            }
#pragma unroll
            for (int i = 0; i < 4; ++i)
#pragma unroll
                for (int j = 0; j < 4; ++j)
                    acc[i][j] = __builtin_amdgcn_mfma_f32_16x16x32_bf16(af[i], bfr[j], acc[i][j], 0, 0, 0);
        }
    }

    const int colInTile = lane & 15;
    const int rquad = lane >> 4;
    float bv[4];
#pragma unroll
    for (int j = 0; j < 4; ++j) bv[j] = bias[gn * 128 + wn * 64 + j * 16 + colInTile];
#pragma unroll
    for (int i = 0; i < 4; ++i) {
#pragma unroll
        for (int j = 0; j < 4; ++j) {
            const int ncol = gn * 128 + wn * 64 + j * 16 + colInTile;
#pragma unroll
            for (int r = 0; r < 4; ++r) {
                const int mrow = gm * 128 + wm * 64 + i * 16 + rquad * 4 + r;
                if (mrow < N_NODES) {
                    float v = acc[i][j][r] + bv[j];
                    out[(size_t)mrow * DIM + ncol] = v > 0.0f ? v : 0.0f;
                }
            }
        }
    }
}

// ---------------- launch ----------------
extern "C" void kernel_launch(void* const* d_in, const int* in_sizes, int n_in,
                              void* d_out, int out_size, void* d_ws, size_t ws_size,
                              hipStream_t stream) {
    const int*   feat = (const int*)d_in[0];
    const int*   src  = (const int*)d_in[1];
    const int*   dst  = (const int*)d_in[2];
    const float* emb  = (const float*)d_in[3];
    const float* Ws0  = (const float*)d_in[4];
    const float* Wn0  = (const float*)d_in[5];
    const float* b0   = (const float*)d_in[6];
    const float* Ws1  = (const float*)d_in[7];
    const float* Wn1  = (const float*)d_in[8];
    const float* b1   = (const float*)d_in[9];
    float* out = (float*)d_out;

    uint8_t* w = (uint8_t*)d_ws;
    auto alloc = [&](size_t bytes) -> void* {
        void* p = (void*)w;
        w += (bytes + 255) & ~(size_t)255;
        return p;
    };
    bf16*     h1      = (bf16*)alloc((size_t)M_PAD * DIM * 2);     // bf16 h1
    uint8_t*  h8      = (uint8_t*)alloc((size_t)M_PAD * DIM);      // fp8 h1 (gather copy, pad rows zeroed)
    bf16*     hn      = (bf16*)alloc((size_t)M_PAD * DIM * 2);     // bf16 neighbor mean
    bf16*     Wt      = (bf16*)alloc((size_t)4 * DIM * DIM * 2);   // Ws1t,Wn1t,Ws0t,Wn0t bf16 [n][k]
    bf16*     embB    = (bf16*)alloc((size_t)128 * DIM * 2);       // emb bf16, padded to 128 rows
    bf16*     Pb      = (bf16*)alloc((size_t)DIM * KEXT * 2);
    bf16*     A0      = (bf16*)alloc((size_t)M_PAD * KEXT * 2);
    int*      cursor  = (int*)alloc((size_t)N_NODES * CURS * 4);   // 1.28 MB, 1 line/node
    int*      csr     = (int*)alloc((size_t)N_NODES * CSTRIDE * 4);// 7.68 MB

    // fused setup: 4x weight transpose + emb bf16 cast + cursor zeroing
    setup_kernel<<<1369, 256, 0, stream>>>(Ws0, Wn0, Ws1, Wn1, emb, Wt, embB, cursor);

    // MFMA projection (replaces 256 MB scalar-FMA proj zone)
    projmm_kernel<<<8, 256, 0, stream>>>(embB, Wt, Pb);

    graph_kernel<<<N_EDGES / 1024, 256, 0, stream>>>(src, dst, feat, cursor, csr);
    normalize_kernel<<<M_PAD / 4, 256, 0, stream>>>(csr, cursor, feat, A0, csr);

    // layer 0 (histogram + one-hot form), emits bf16 h1 and fp8 h8
    gemm0_kernel<<<dim3(4, 157), 256, 0, stream>>>(A0, Pb, b0, h1, h8);

    // layer 1
    aggregate_kernel<<<dim3(5000, 4), 256, 0, stream>>>(h8, cursor, csr, hn);
    gemm1_kernel<<<dim3(4, 157), 256, 0, stream>>>(
        h1, hn, Wt, Wt + DIM * DIM, b1, out);
}

// Round 15
// 231.679 us; speedup vs baseline: 1.1319x; 1.0363x over previous
//
#include <hip/hip_runtime.h>
#include <hip/hip_bf16.h>
#include <stdint.h>

#define N_NODES 20000
#define N_EDGES 640000
#define DIM     512
#define M_PAD   20096   // 157 * 128
#define NTYPE   100
#define KEXT    256     // 128 histogram + 128 one-hot
#define CSTRIDE 96      // fixed CSR row stride; Poisson(32) max-deg ~58 over 20K draws
#define CURS    16      // cursor padding: one 64 B line per node (atomic de-contention)

using bf16 = __hip_bfloat16;
typedef __attribute__((ext_vector_type(4))) float floatx4;
typedef __attribute__((ext_vector_type(2))) float floatx2;
typedef __attribute__((ext_vector_type(8))) short short8;

// async global->LDS, 16B per lane. LDS dest is wave-uniform base + lane*16.
__device__ __forceinline__ void async16(const void* g, void* l) {
    __builtin_amdgcn_global_load_lds(
        (const __attribute__((address_space(1))) void*)g,
        (__attribute__((address_space(3))) void*)l, 16, 0, 0);
}

__device__ __forceinline__ uint8_t f32_to_fp8(float v) {
    unsigned p = (unsigned)__builtin_amdgcn_cvt_pk_fp8_f32(v, v, 0, false);
    return (uint8_t)(p & 0xffu);
}

// ---------------- fused setup ----------------
// blocks [0,1024): transpose {Ws1,Wn1,Ws0,Wn0} fp32[k][n] -> Wt[w][n][k] bf16
// blocks [1024,1056): cast emb -> embB [128][512] bf16 (t>=100 zeroed)
// blocks [1056,1369): zero cursor (80000 uint4)
__global__ __launch_bounds__(256)
void setup_kernel(const float* __restrict__ Ws0, const float* __restrict__ Wn0,
                  const float* __restrict__ Ws1, const float* __restrict__ Wn1,
                  const float* __restrict__ emb, bf16* __restrict__ Wt,
                  bf16* __restrict__ embB, int* __restrict__ cursor) {
    __shared__ float tile[32][33];
    const int b = blockIdx.x;
    const int tid = threadIdx.x;
    if (b < 1024) {
        const int w = b >> 8;                          // 0:Ws1 1:Wn1 2:Ws0 3:Wn0
        const int rem = b & 255;
        const int k0 = (rem & 15) * 32;
        const int n0 = (rem >> 4) * 32;
        const float* W = (w == 0) ? Ws1 : (w == 1) ? Wn1 : (w == 2) ? Ws0 : Wn0;
        const int tx = tid & 31, ty = tid >> 5;
#pragma unroll
        for (int i = 0; i < 4; ++i)
            tile[ty + i * 8][tx] = W[(size_t)(k0 + ty + i * 8) * DIM + n0 + tx];
        __syncthreads();
        bf16* O = Wt + (size_t)w * DIM * DIM;
#pragma unroll
        for (int i = 0; i < 4; ++i)
            O[(size_t)(n0 + ty + i * 8) * DIM + k0 + tx] = __float2bfloat16(tile[tx][ty + i * 8]);
    } else if (b < 1056) {
        const int idx = (b - 1024) * 2048 + tid * 8;   // [0, 65536), 8 elems/thread
        const int t = idx >> 9;
        union { uint4 u; bf16 v[8]; } o;
        if (t < NTYPE) {
            const float* e = emb + idx;
#pragma unroll
            for (int q = 0; q < 8; ++q) o.v[q] = __float2bfloat16(e[q]);
        } else {
#pragma unroll
            for (int q = 0; q < 8; ++q) o.v[q] = __float2bfloat16(0.0f);
        }
        *(uint4*)(embB + idx) = o.u;
    } else {
        const int idx = (b - 1056) * 256 + tid;
        if (idx < (N_NODES * CURS) / 4) {
            uint4 z; z.x = 0; z.y = 0; z.z = 0; z.w = 0;
            ((uint4*)cursor)[idx] = z;
        }
    }
}

// ---------------- merged dispatch: graph CSR fill (b<625) || MFMA proj (625<=b<633) ----------------
// Independent zones: graph is atomic-latency-bound (VALUBusy ~0.5%), projmm is MFMA-bound —
// projmm hides completely under graph.
__global__ __launch_bounds__(256)
void graph_proj_kernel(const int* __restrict__ src, const int* __restrict__ dst,
                       const int* __restrict__ feat, int* __restrict__ cursor,
                       int* __restrict__ csr, const bf16* __restrict__ embB,
                       const bf16* __restrict__ Wt, bf16* __restrict__ Pb) {
    const int b = blockIdx.x;
    const int tid = threadIdx.x;
    if (b < 625) {
        // ---- CSR fill: 4 edges/thread, independent atomic chains, feat packed ----
        const int idx = b * 256 + tid;                 // 160000 threads x 4 edges
        const int4 s4 = ((const int4*)src)[idx];
        const int4 d4 = ((const int4*)dst)[idx];
        const int s[4] = {s4.x, s4.y, s4.z, s4.w};
        const int d[4] = {d4.x, d4.y, d4.z, d4.w};
        int t[4], p[4];
#pragma unroll
        for (int q = 0; q < 4; ++q) t[q] = feat[s[q]];
#pragma unroll
        for (int q = 0; q < 4; ++q) p[q] = atomicAdd(&cursor[d[q] * CURS], 1);
#pragma unroll
        for (int q = 0; q < 4; ++q)
            if (p[q] < CSTRIDE) csr[d[q] * CSTRIDE + p[q]] = s[q] | (t[q] << 16);
    } else {
        // ---- projmm: Pb = (embB @ {Ws0t;Wn0t}^T)^T scatter.  M=128(t), N'=1024, K=512 ----
        const int gn = b - 625;
        const int lane = tid & 63, wave = tid >> 6;
        const int wm = wave & 1, wn = wave >> 1;
        const int lrow = lane & 15;
        const int kq = lane >> 4;
        const bf16* WB = Wt + (size_t)2 * DIM * DIM;   // Ws0t rows 0..511, Wn0t rows 512..1023
        floatx4 acc[4][4] = {};
#pragma unroll 4
        for (int kk = 0; kk < DIM; kk += 32) {
            short8 af[4], bfr[4];
#pragma unroll
            for (int i = 0; i < 4; ++i)
                af[i] = *(const short8*)(embB + (size_t)(wm * 64 + i * 16 + lrow) * DIM + kk + kq * 8);
#pragma unroll
            for (int j = 0; j < 4; ++j)
                bfr[j] = *(const short8*)(WB + (size_t)(gn * 128 + wn * 64 + j * 16 + lrow) * DIM + kk + kq * 8);
#pragma unroll
            for (int i = 0; i < 4; ++i)
#pragma unroll
                for (int j = 0; j < 4; ++j)
                    acc[i][j] = __builtin_amdgcn_mfma_f32_16x16x32_bf16(af[i], bfr[j], acc[i][j], 0, 0, 0);
        }
        const int colInTile = lane & 15;
        const int rquad = lane >> 4;
#pragma unroll
        for (int i = 0; i < 4; ++i)
#pragma unroll
            for (int j = 0; j < 4; ++j) {
                const int np = gn * 128 + wn * 64 + j * 16 + colInTile;
#pragma unroll
                for (int r = 0; r < 4; ++r) {
                    const int t = wm * 64 + i * 16 + rquad * 4 + r;
                    const int n = np & 511;
                    const int pcol = (np < 512) ? (128 + t) : t;
                    Pb[(size_t)n * KEXT + pcol] = __float2bfloat16(acc[i][j][r]);
                }
            }
    }
}

// ---------------- A0 [M_PAD][KEXT] from CSR via LDS hist; pads csr rows to mult-of-16 ----------------
// Pad entries point at row N_NODES (zeroed in h8 by gemm0) so aggregate needs no predication.
__global__ void normalize_kernel(const int* __restrict__ csr, const int* __restrict__ cursor,
                                 const int* __restrict__ feat, bf16* __restrict__ A0,
                                 int* __restrict__ csr_w) {
    __shared__ int hist[4 * 128];
    const int tid = threadIdx.x;
    hist[tid] = 0;
    hist[tid + 256] = 0;
    __syncthreads();
    const int wave = tid >> 6, lane = tid & 63;
    const int node = blockIdx.x * 4 + wave;            // grid.x = 5024 exactly
    int dg = 0;
    if (node < N_NODES) {
        dg = cursor[node * CURS];
        if (dg > CSTRIDE) dg = CSTRIDE;
        for (int l = lane; l < dg; l += 64) {
            const int v = csr[node * CSTRIDE + l];
            atomicAdd(&hist[wave * 128 + (v >> 16)], 1);
        }
        const int dgp = (dg + 15) & ~15;               // <= 96 = CSTRIDE
        for (int l = dg + lane; l < dgp; l += 64)
            csr_w[node * CSTRIDE + l] = N_NODES;
    }
    __syncthreads();
    const int c = lane * 4;                            // cols c..c+3 of KEXT
    union { uint2 u; bf16 b[4]; } o;
    if (node < N_NODES) {
        if (c < 128) {
            const float inv = 1.0f / (float)(dg > 0 ? dg : 1);
#pragma unroll
            for (int q = 0; q < 4; ++q)
                o.b[q] = __float2bfloat16((float)hist[wave * 128 + c + q] * inv);
        } else {
            const int f = feat[node];
#pragma unroll
            for (int q = 0; q < 4; ++q)
                o.b[q] = __float2bfloat16((c - 128 + q == f) ? 1.0f : 0.0f);
        }
    } else {
#pragma unroll
        for (int q = 0; q < 4; ++q) o.b[q] = __float2bfloat16(0.0f);
    }
    *(uint2*)(A0 + (size_t)node * KEXT + c) = o.u;
}

// ---------------- mean aggregation: plane-split, 16 edges/iter (R10/R12 optimum), 32-bit addr ----------------
// grid (5000, 4): y = plane (128 B slice; 2.5 MB L2-resident working set, x-major dispatch).
__global__ void aggregate_kernel(const uint8_t* __restrict__ h8, const int* __restrict__ cursor,
                                 const int* __restrict__ csr, bf16* __restrict__ hn) {
    const int tid = threadIdx.x;
    const int nb = blockIdx.x;                         // node group, grid.x = 5000
    const int p = blockIdx.y;
    const int wave = tid >> 6, lane = tid & 63;
    const int node = nb * 4 + wave;
    int dg = cursor[node * CURS];
    if (dg > CSTRIDE) dg = CSTRIDE;
    const int dgp = (dg + 15) & ~15;                   // csr padded by normalize
    const int eg = lane >> 3, sc = lane & 7;
    const int base = node * CSTRIDE;
    const unsigned colb = p * 128 + sc * 16;           // byte offset in fp8 row
    floatx2 acc[8] = {};                               // acc[a] = dims (2a, 2a+1) of lane's 16

    for (int i = 0; i < dgp; i += 16) {
        const unsigned s0 = (unsigned)(csr[base + i + eg]     & 0xffff);
        const unsigned s1 = (unsigned)(csr[base + i + 8 + eg] & 0xffff);
        const uint4 r0 = *(const uint4*)(h8 + ((s0 << 9) + colb));
        const uint4 r1 = *(const uint4*)(h8 + ((s1 << 9) + colb));
        const unsigned v0[4] = {r0.x, r0.y, r0.z, r0.w};
        const unsigned v1[4] = {r1.x, r1.y, r1.z, r1.w};
#pragma unroll
        for (int q = 0; q < 4; ++q) {
            acc[2 * q]     += __builtin_amdgcn_cvt_pk_f32_fp8((int)v0[q], false);
            acc[2 * q + 1] += __builtin_amdgcn_cvt_pk_f32_fp8((int)v0[q], true);
        }
#pragma unroll
        for (int q = 0; q < 4; ++q) {
            acc[2 * q]     += __builtin_amdgcn_cvt_pk_f32_fp8((int)v1[q], false);
            acc[2 * q + 1] += __builtin_amdgcn_cvt_pk_f32_fp8((int)v1[q], true);
        }
    }
#pragma unroll
    for (int mk = 8; mk <= 32; mk <<= 1)
#pragma unroll
        for (int q = 0; q < 8; ++q) {
            float lo = acc[q][0], hi = acc[q][1];
            acc[q][0] = lo + __shfl_xor(lo, mk, 64);
            acc[q][1] = hi + __shfl_xor(hi, mk, 64);
        }

    if (eg == 0) {
        const float scale = 1.0f / (float)(dg > 0 ? dg : 1);
        union { uint4 u; bf16 b[8]; } o0, o1;
#pragma unroll
        for (int q = 0; q < 4; ++q) {
            o0.b[2 * q]     = __float2bfloat16(acc[q][0] * scale);
            o0.b[2 * q + 1] = __float2bfloat16(acc[q][1] * scale);
            o1.b[2 * q]     = __float2bfloat16(acc[4 + q][0] * scale);
            o1.b[2 * q + 1] = __float2bfloat16(acc[4 + q][1] * scale);
        }
        bf16* outp = hn + (size_t)node * DIM + colb;
        *(uint4*)outp = o0.u;
        *(uint4*)(outp + 8) = o1.u;
    }
}

// ---------------- layer-0 GEMM (LDS-staged): h1 = relu(A0 @ Pb^T + b0) -> bf16 h1 + fp8 h8 ----------------
// K=256, BK=64 (4 iters), XOR-swizzled global_load_lds staging, 32 KB LDS, 4 blocks/CU.
__global__ __launch_bounds__(256, 4)
void gemm0_kernel(const bf16* __restrict__ A0, const bf16* __restrict__ Pb,
                  const float* __restrict__ bias, bf16* __restrict__ h1,
                  uint8_t* __restrict__ h8) {
    __shared__ bf16 As[128 * 64];
    __shared__ bf16 Bs[128 * 64];
    const int tid  = threadIdx.x;
    const int lane = tid & 63;
    const int wave = tid >> 6;
    const int wm = wave & 1, wn = wave >> 1;
    const int gn = blockIdx.x, gm = blockIdx.y;        // gm slow: A-tile temporal locality
    const int lrow = lane & 15;
    const int kq   = lane >> 4;

    floatx4 acc[4][4] = {};
    for (int kt = 0; kt < 4; ++kt) {
        const int k0 = kt * 64;
        __syncthreads();                               // protect LDS reuse
#pragma unroll
        for (int it = 0; it < 4; ++it) {
            const int chunk = tid + it * 256;          // LDS chunk (uniform base + lane*16)
            const int row = chunk >> 3;
            const int ch  = (chunk & 7) ^ (row & 7);   // swizzled global source
            async16(A0 + (size_t)(gm * 128 + row) * KEXT + k0 + ch * 8, As + chunk * 8);
            async16(Pb + (size_t)(gn * 128 + row) * KEXT + k0 + ch * 8, Bs + chunk * 8);
        }
        __syncthreads();                               // staging complete
#pragma unroll
        for (int kk8 = 0; kk8 < 8; kk8 += 4) {
            short8 af[4], bfr[4];
#pragma unroll
            for (int i = 0; i < 4; ++i) {
                const int r = wm * 64 + i * 16 + lrow;
                af[i] = *(const short8*)(As + (r * 8 + ((kq + kk8) ^ (r & 7))) * 8);
            }
#pragma unroll
            for (int j = 0; j < 4; ++j) {
                const int r = wn * 64 + j * 16 + lrow;
                bfr[j] = *(const short8*)(Bs + (r * 8 + ((kq + kk8) ^ (r & 7))) * 8);
            }
#pragma unroll
            for (int i = 0; i < 4; ++i)
#pragma unroll
                for (int j = 0; j < 4; ++j)
                    acc[i][j] = __builtin_amdgcn_mfma_f32_16x16x32_bf16(af[i], bfr[j], acc[i][j], 0, 0, 0);
        }
    }

    // C/D layout: col=lane&15, row=(lane>>4)*4+reg  [m89/m91]
    const int colInTile = lane & 15;
    const int rquad = lane >> 4;
    float bv[4];
#pragma unroll
    for (int j = 0; j < 4; ++j) bv[j] = bias[gn * 128 + wn * 64 + j * 16 + colInTile];
#pragma unroll
    for (int i = 0; i < 4; ++i) {
#pragma unroll
        for (int r = 0; r < 4; ++r) {
            const int mrow = gm * 128 + wm * 64 + i * 16 + rquad * 4 + r;
            if (mrow >= N_NODES) {
                if (mrow < M_PAD) {
#pragma unroll
                    for (int j = 0; j < 4; ++j) {
                        const int ncol = gn * 128 + wn * 64 + j * 16 + colInTile;
                        h1[(size_t)mrow * DIM + ncol] = __float2bfloat16(0.0f);
                        h8[(size_t)mrow * DIM + ncol] = 0;   // zero rows incl. the pad target
                    }
                }
                continue;
            }
#pragma unroll
            for (int j = 0; j < 4; ++j) {
                const int ncol = gn * 128 + wn * 64 + j * 16 + colInTile;
                float v = acc[i][j][r] + bv[j];
                v = v > 0.0f ? v : 0.0f;
                h1[(size_t)mrow * DIM + ncol] = __float2bfloat16(v);
                h8[(size_t)mrow * DIM + ncol] = f32_to_fp8(v);
            }
        }
    }
}

// ---------------- layer-1 fused dual-GEMM bf16 (K=1024): XOR-swizzled single-buffer LDS ----------------
__global__ __launch_bounds__(256, 4)
void gemm1_kernel(const bf16* __restrict__ A, const bf16* __restrict__ Nh,
                  const bf16* __restrict__ Bst, const bf16* __restrict__ Bnt,
                  const float* __restrict__ bias, float* __restrict__ out) {
    __shared__ bf16 As[128 * 64];
    __shared__ bf16 Bs[128 * 64];
    const int tid  = threadIdx.x;
    const int lane = tid & 63;
    const int wave = tid >> 6;
    const int wm = wave & 1, wn = wave >> 1;
    const int gn = blockIdx.x, gm = blockIdx.y;        // gm slow: A-tile temporal locality

    floatx4 acc[4][4] = {};
    const int lrow = lane & 15;
    const int kq   = lane >> 4;

    for (int kt = 0; kt < 16; ++kt) {
        const bf16* Ap = (kt < 8) ? A : Nh;
        const bf16* Bp = (kt < 8) ? Bst : Bnt;
        const int k0 = (kt & 7) * 64;
        __syncthreads();                               // protect LDS reuse
#pragma unroll
        for (int it = 0; it < 4; ++it) {
            const int chunk = tid + it * 256;          // LDS chunk (uniform base + lane*16)
            const int row = chunk >> 3;
            const int ch  = (chunk & 7) ^ (row & 7);   // swizzled global source
            async16(Ap + (size_t)(gm * 128 + row) * DIM + k0 + ch * 8, As + chunk * 8);
            async16(Bp + (size_t)(gn * 128 + row) * DIM + k0 + ch * 8, Bs + chunk * 8);
        }
        __syncthreads();                               // staging complete (vmcnt drained)
#pragma unroll
        for (int kk8 = 0; kk8 < 8; kk8 += 4) {
            short8 af[4], bfr[4];
#pragma unroll
            for (int i = 0; i < 4; ++i) {
                const int r = wm * 64 + i * 16 + lrow;
                af[i] = *(const short8*)(As + (r * 8 + ((kq + kk8) ^ (r & 7))) * 8);
            }
#pragma unroll
            for (int j = 0; j < 4; ++j) {
                const int r = wn * 64 + j * 16 + lrow;
                bfr[j] = *(const short8*)(Bs + (r * 8 + ((kq + kk8) ^ (r & 7))) * 8);
            }
#pragma unroll
            for (int i = 0; i < 4; ++i)
#pragma unroll
                for (int j = 0; j < 4; ++j)
                    acc[i][j] = __builtin_amdgcn_mfma_f32_16x16x32_bf16(af[i], bfr[j], acc[i][j], 0, 0, 0);
        }
    }

    const int colInTile = lane & 15;
    const int rquad = lane >> 4;
    float bv[4];
#pragma unroll
    for (int j = 0; j < 4; ++j) bv[j] = bias[gn * 128 + wn * 64 + j * 16 + colInTile];
#pragma unroll
    for (int i = 0; i < 4; ++i) {
#pragma unroll
        for (int j = 0; j < 4; ++j) {
            const int ncol = gn * 128 + wn * 64 + j * 16 + colInTile;
#pragma unroll
            for (int r = 0; r < 4; ++r) {
                const int mrow = gm * 128 + wm * 64 + i * 16 + rquad * 4 + r;
                if (mrow < N_NODES) {
                    float v = acc[i][j][r] + bv[j];
                    out[(size_t)mrow * DIM + ncol] = v > 0.0f ? v : 0.0f;
                }
            }
        }
    }
}

// ---------------- launch ----------------
extern "C" void kernel_launch(void* const* d_in, const int* in_sizes, int n_in,
                              void* d_out, int out_size, void* d_ws, size_t ws_size,
                              hipStream_t stream) {
    const int*   feat = (const int*)d_in[0];
    const int*   src  = (const int*)d_in[1];
    const int*   dst  = (const int*)d_in[2];
    const float* emb  = (const float*)d_in[3];
    const float* Ws0  = (const float*)d_in[4];
    const float* Wn0  = (const float*)d_in[5];
    const float* b0   = (const float*)d_in[6];
    const float* Ws1  = (const float*)d_in[7];
    const float* Wn1  = (const float*)d_in[8];
    const float* b1   = (const float*)d_in[9];
    float* out = (float*)d_out;

    uint8_t* w = (uint8_t*)d_ws;
    auto alloc = [&](size_t bytes) -> void* {
        void* p = (void*)w;
        w += (bytes + 255) & ~(size_t)255;
        return p;
    };
    bf16*     h1      = (bf16*)alloc((size_t)M_PAD * DIM * 2);     // bf16 h1
    uint8_t*  h8      = (uint8_t*)alloc((size_t)M_PAD * DIM);      // fp8 h1 (gather copy, pad rows zeroed)
    bf16*     hn      = (bf16*)alloc((size_t)M_PAD * DIM * 2);     // bf16 neighbor mean
    bf16*     Wt      = (bf16*)alloc((size_t)4 * DIM * DIM * 2);   // Ws1t,Wn1t,Ws0t,Wn0t bf16 [n][k]
    bf16*     embB    = (bf16*)alloc((size_t)128 * DIM * 2);       // emb bf16, padded to 128 rows
    bf16*     Pb      = (bf16*)alloc((size_t)DIM * KEXT * 2);
    bf16*     A0      = (bf16*)alloc((size_t)M_PAD * KEXT * 2);
    int*      cursor  = (int*)alloc((size_t)N_NODES * CURS * 4);   // 1.28 MB, 1 line/node
    int*      csr     = (int*)alloc((size_t)N_NODES * CSTRIDE * 4);// 7.68 MB

    // fused setup: 4x weight transpose + emb bf16 cast + cursor zeroing
    setup_kernel<<<1369, 256, 0, stream>>>(Ws0, Wn0, Ws1, Wn1, emb, Wt, embB, cursor);

    // merged: CSR fill (625 blocks) || MFMA projection (8 blocks)
    graph_proj_kernel<<<633, 256, 0, stream>>>(src, dst, feat, cursor, csr, embB, Wt, Pb);

    normalize_kernel<<<M_PAD / 4, 256, 0, stream>>>(csr, cursor, feat, A0, csr);

    // layer 0 (histogram + one-hot form), emits bf16 h1 and fp8 h8
    gemm0_kernel<<<dim3(4, 157), 256, 0, stream>>>(A0, Pb, b0, h1, h8);

    // layer 1
    aggregate_kernel<<<dim3(5000, 4), 256, 0, stream>>>(h8, cursor, csr, hn);
    gemm1_kernel<<<dim3(4, 157), 256, 0, stream>>>(
        h1, hn, Wt, Wt + DIM * DIM, b1, out);
}